// Round 8
// baseline (15133.838 us; speedup 1.0000x reference)
//
#include <hip/hip_runtime.h>
#include <math.h>

typedef __attribute__((ext_vector_type(4))) int i32x4;

constexpr int kB  = 128;
constexpr int kT  = 1024;
constexpr int kD  = 32;
constexpr int kH  = 64;
constexpr int kW  = 128;
constexpr int kC  = kD + 1;    // 33  (initial-MLP input width; iW0 is [128][33])
constexpr int kO  = kH * kC;   // 2112
constexpr int kIN = kH + 1;    // 65  (vf input width; vW0 is [128][65])
constexpr int BPB   = 16;      // batches per block
constexpr int NBLK  = kB / BPB;// 8 blocks
constexpr int BLOCK = 1024;    // 16 waves

// ---- workspace byte layout (i8 two-plane weights + f32 scales) ----
// W2: 132 M-tiles; per tile: [kc(2)][plane(2)] x 64 lanes x 16 bytes.
//   byte addr = ((M*2+kc)*2+p)*1024 + lane*16 + j ; value = plane of
//   W2[16M + (lane&15)][64kc + 16(lane>>4) + j], plane0=hi, plane1=lo.
constexpr int W2B  = 0;        // 132*4096 = 540672
constexpr int W1B  = 540672;   // 8 tiles * 4096 = 32768
constexpr int W0B  = 573440;   // 8 tiles * 2048 = 16384 (K=64: cols 1..64)
constexpr int SC2W = 147456;   // u32 index (byte 589824): 2112 f32 row scales
constexpr int SC1W = 149568;   // 128 f32
constexpr int SC0W = 149696;   // 128 f32
constexpr int WS_TOT = 149952; // u32 -> 599808 bytes

constexpr float QA = 8323072.0f;   // activation quant target (~2^23)

__device__ __forceinline__ float fast_sigmoid(float x) { return 1.0f / (1.0f + __expf(-x)); }
__device__ __forceinline__ float lipswish_f(float x)   { return 0.909f * x * fast_sigmoid(x); }
__device__ __forceinline__ float fast_tanh(float x) {
    float ax = fabsf(x);
    float e  = __expf(2.0f * ax);
    float r  = 1.0f - 2.0f / (e + 1.0f);
    return copysignf(r, x);
}
__device__ __forceinline__ float dot4(float4 a, float4 b) {
    return a.x * b.x + a.y * b.y + a.z * b.z + a.w * b.w;
}
// exact int16 -> (hi,lo) i8 planes: q = 256*hi + lo
__device__ __forceinline__ void split16(int q, int& lo, int& hi) {
    lo = (int)(signed char)(q & 0xFF);
    hi = (q - lo) >> 8;
}
__device__ __forceinline__ int q15c(float v, float inv) {
    float q = rintf(v * inv);
    q = fmaxf(-32511.0f, fminf(32511.0f, q));
    return (int)q;
}
// int24 activation: q = 65536*a2 + 256*a1 + a0, all i8; exact for |q|<=8355711
__device__ __forceinline__ int q24c(float v, float inv) {
    float q = rintf(v * inv);
    q = fmaxf(-8355711.0f, fminf(8355711.0f, q));
    return (int)q;
}
__device__ __forceinline__ void split24(int q, int& a0, int& a1, int& a2) {
    a0 = (int)(signed char)(q & 0xFF);
    int r = (q - a0) >> 8;
    a1 = (int)(signed char)(r & 0xFF);
    a2 = (r - a1) >> 8;
}
__device__ __forceinline__ i32x4 mmi8(uint4 a, uint4 b, i32x4 c) {
    union { uint4 u; i32x4 v; } ua, ub;
    ua.u = a; ub.u = b;
    return __builtin_amdgcn_mfma_i32_16x16x64_i8(ua.v, ub.v, c, 0, 0, 0);
}

// one wave per weight row; rows: [0,2112) vW2, [2112,2240) vW1, [2240,2368) vW0
__global__ __launch_bounds__(64)
void prep_kernel(const float* __restrict__ vW0, const float* __restrict__ vW1,
                 const float* __restrict__ vW2, unsigned* __restrict__ ws)
{
    const int row = blockIdx.x, ln = threadIdx.x;
    char*  wb  = (char*)ws;
    float* scf = (float*)ws;

    if (row < kO) {
        const float* src = vW2 + (size_t)row * kW;
        float m = fmaxf(fabsf(src[ln]), fabsf(src[ln + 64]));
        #pragma unroll
        for (int s = 1; s < 64; s <<= 1) m = fmaxf(m, __shfl_xor(m, s));
        float inv = (m > 0.f) ? 32511.f / m : 0.f;
        if (ln == 0) scf[SC2W + row] = (m > 0.f) ? m / 32511.f : 0.f;
        const int M = row >> 4, ri = row & 15;
        #pragma unroll
        for (int h = 0; h < 2; h++) {
            int c = ln + 64 * h;               // kc = h
            int q = q15c(src[c], inv);
            int lo, hi; split16(q, lo, hi);
            int lp = ((c & 63) >> 4) * 16 + ri, j = c & 15;
            size_t base = (size_t)W2B + (size_t)((M * 2 + h) * 2) * 1024 + lp * 16 + j;
            wb[base]        = (char)hi;
            wb[base + 1024] = (char)lo;
        }
    } else if (row < kO + kW) {
        const int r = row - kO;
        const float* src = vW1 + (size_t)r * kW;
        float m = fmaxf(fabsf(src[ln]), fabsf(src[ln + 64]));
        #pragma unroll
        for (int s = 1; s < 64; s <<= 1) m = fmaxf(m, __shfl_xor(m, s));
        float inv = (m > 0.f) ? 32511.f / m : 0.f;
        if (ln == 0) scf[SC1W + r] = (m > 0.f) ? m / 32511.f : 0.f;
        const int M = r >> 4, ri = r & 15;
        #pragma unroll
        for (int h = 0; h < 2; h++) {
            int c = ln + 64 * h;
            int q = q15c(src[c], inv);
            int lo, hi; split16(q, lo, hi);
            int lp = ((c & 63) >> 4) * 16 + ri, j = c & 15;
            size_t base = (size_t)W1B + (size_t)((M * 2 + h) * 2) * 1024 + lp * 16 + j;
            wb[base]        = (char)hi;
            wb[base + 1024] = (char)lo;
        }
    } else {
        const int r = row - kO - kW;
        const float* src = vW0 + (size_t)r * kIN;
        float m = fabsf(src[ln + 1]);          // cols 1..64 (col0 stays f32)
        #pragma unroll
        for (int s = 1; s < 64; s <<= 1) m = fmaxf(m, __shfl_xor(m, s));
        float inv = (m > 0.f) ? 32511.f / m : 0.f;
        if (ln == 0) scf[SC0W + r] = (m > 0.f) ? m / 32511.f : 0.f;
        const int M = r >> 4, ri = r & 15;
        int k = ln;                             // k = c-1
        int q = q15c(src[k + 1], inv);
        int lo, hi; split16(q, lo, hi);
        int lp = (k >> 4) * 16 + ri, j = k & 15;
        size_t base = (size_t)W0B + (size_t)(M * 2) * 1024 + lp * 16 + j;
        wb[base]        = (char)hi;
        wb[base + 1024] = (char)lo;
    }
}

// 16 batches/block, 8 blocks. i8 matrix pipe; int16 two-plane weights (exact),
// int24 three-plane activations (round-8: was int16 -> absmax 24; the extra
// plane shares accumulators by scale group so MFMA count is 5/4 of round 7).
__global__ __attribute__((amdgpu_flat_work_group_size(1024, 1024), amdgpu_waves_per_eu(4, 4)))
void cde_kernel(
    const float* __restrict__ ts,  const float* __restrict__ ys,
    const float* __restrict__ iW0, const float* __restrict__ ib0,
    const float* __restrict__ iW1, const float* __restrict__ ib1,
    const float* __restrict__ iW2, const float* __restrict__ ib2,
    const float* __restrict__ vW0, const float* __restrict__ vb0,
    const float* __restrict__ vW1, const float* __restrict__ vb1,
    const float* __restrict__ vW2, const float* __restrict__ vb2,
    const float* __restrict__ rW,  const float* __restrict__ rb,
    const unsigned* __restrict__ wsb,
    float* __restrict__ out)
{
    const int t   = threadIdx.x;
    const int wv  = t >> 6;
    const int ln  = t & 63;
    const int bq  = ln & 15;       // MFMA C column = batch
    const int bG0 = blockIdx.x * BPB;

    __shared__ __align__(16) uint4 s_inpq[3][64];       // yhat planes [a2,a1,a0]
    __shared__ __align__(16) uint4 s_z1q[2][3][64];     // [kc][plane][lane]
    __shared__ __align__(16) uint4 s_z2q[2][3][64];
    __shared__ __align__(16) unsigned short s_v[16 * 2178]; // v int16 [b][h*34+c]
    __shared__ float s_y[16 * 65], s_yh[16 * 65], s_e[16 * 65]; // [b*65+h]
    __shared__ float s_dx[2][16][34];
    __shared__ float s_red[16];
    __shared__ float s_scales[4];  // [0]=inp,[1]=z1,[2]=z2  (= gm/QA)

    const uint4* w2q = (const uint4*)wsb;
    const uint4* w1q = (const uint4*)((const char*)wsb + W1B);
    const uint4* w0q = (const uint4*)((const char*)wsb + W0B);
    const float* scf = (const float*)wsb;

    // ---- initial MLP (one-time, f32) on scratch overlaid in s_v ----
    {
        float* s_x0 = (float*)s_v;           // [16][33]
        float* s_zA = (float*)s_v + 528;     // [16][128]
        float* s_zB = (float*)s_v + 2576;    // [16][128]
        for (int idx = t; idx < BPB * kC; idx += BLOCK) {
            int b = idx / kC, c = idx - b * kC;
            s_x0[idx] = (c == 0) ? ts[0] : ys[(size_t)(bG0 + b) * kT * kD + (c - 1)];
        }
        __syncthreads();
        {
            const int row = t & 127, bb = t >> 7;
            float a0 = ib0[row], a1 = a0;
            const float* wr = iW0 + (size_t)row * kC;
            for (int c = 0; c < kC; c++) {
                float w = wr[c];
                a0 += w * s_x0[bb * kC + c];
                a1 += w * s_x0[(bb + 8) * kC + c];
            }
            s_zA[bb * kW + row]       = fmaxf(a0, 0.f);
            s_zA[(bb + 8) * kW + row] = fmaxf(a1, 0.f);
        }
        __syncthreads();
        {
            const int row = t & 127, bb = t >> 7;
            float a0 = ib1[row], a1 = a0;
            const float* wr = iW1 + (size_t)row * kW;
            for (int c = 0; c < kW; c++) {
                float w = wr[c];
                a0 += w * s_zA[bb * kW + c];
                a1 += w * s_zA[(bb + 8) * kW + c];
            }
            s_zB[bb * kW + row]       = fmaxf(a0, 0.f);
            s_zB[(bb + 8) * kW + row] = fmaxf(a1, 0.f);
        }
        __syncthreads();
        float a = 0.f;
        {
            const int row = t & 63, b = t >> 6;
            a = ib2[row];
            const float* wr = iW2 + (size_t)row * kW;
            for (int c = 0; c < kW; c++) a += wr[c] * s_zB[b * kW + c];
            float am = fabsf(a);
            #pragma unroll
            for (int s = 1; s < 64; s <<= 1) am = fmaxf(am, __shfl_xor(am, s));
            if (ln == 0) s_red[wv] = am;
        }
        __syncthreads();
        // y/yhat init + int24 yhat0 fragments (scratch consumers done)
        {
            const int row = t & 63, b = t >> 6;
            s_y[b * 65 + row]  = a;
            s_yh[b * 65 + row] = a;
            float gm = s_red[0];
            #pragma unroll
            for (int k = 1; k < 16; k++) gm = fmaxf(gm, s_red[k]);
            float inv = (gm > 0.f) ? QA / gm : 0.f;
            int q = q24c(a, inv);
            int a0p, a1p, a2p; split24(q, a0p, a1p, a2p);
            int lp = (row >> 4) * 16 + b, jj = row & 15;
            char* ib = (char*)s_inpq;
            ib[lp * 16 + jj]        = (char)a2p;
            ib[1024 + lp * 16 + jj] = (char)a1p;
            ib[2048 + lp * 16 + jj] = (char)a0p;
            if (t == 0) s_scales[0] = gm / QA;
        }
    }
    // dx prefetch registers: thread (bd, cd) owns x[bd][cd]
    int bd = 0, cd = 0;
    float x_reg = 0.f, x_next = 0.f;
    const float* yptr = nullptr;
    const bool isdx = (t < BPB * kC);   // 528 threads
    if (isdx) {
        bd = t / kC; cd = t - bd * kC;
        if (cd == 0) { x_reg = ts[0]; x_next = ts[1]; }
        else {
            const float* pp = ys + (size_t)(bG0 + bd) * kT * kD + (cd - 1);
            x_reg = pp[0]; x_next = pp[kD]; yptr = pp + 2 * kD;
        }
        s_dx[0][bd][cd] = 0.f;
    }
    __syncthreads();

    const i32x4 zz = {0, 0, 0, 0};

    // ---- main scan: 7 barriers/step ----
    for (int i = 0; i < kT; i++) {
        // ===== PhA: layer1 MFMA (waves 8-15) + dx staging (t<528) =====
        float z1v[4] = {0.f, 0.f, 0.f, 0.f};
        float amA = 0.f;
        if (wv >= 8) {
            const int M = wv - 8;
            uint4 wh = w0q[M * 128 + ln], wl = w0q[M * 128 + 64 + ln];
            uint4 i2 = s_inpq[0][ln], i1 = s_inpq[1][ln], i0 = s_inpq[2][ln];
            i32x4 A = mmi8(wh, i2, zz);                      // x 2^24
            i32x4 B = mmi8(wh, i1, zz); B = mmi8(wl, i2, B); // x 2^16
            i32x4 C = mmi8(wh, i0, zz); C = mmi8(wl, i1, C); // x 2^8
            const float sinp = s_scales[0];
            const float tc = ts[i];
            const int r0 = 16 * M + 4 * (ln >> 4);
            #pragma unroll
            for (int r = 0; r < 4; r++) {
                int rw = r0 + r;
                float raw = 16777216.f * (float)A[r] + 65536.f * (float)B[r] + 256.f * (float)C[r];
                float pre = scf[SC0W + rw] * sinp * raw + vW0[(size_t)rw * kIN] * tc + vb0[rw];
                z1v[r] = lipswish_f(pre);
                amA = fmaxf(amA, fabsf(z1v[r]));
            }
            #pragma unroll
            for (int s = 1; s < 64; s <<= 1) amA = fmaxf(amA, __shfl_xor(amA, s));
            if (ln == 0) s_red[wv] = amA;
        }
        if (isdx && i + 1 < kT) {
            float dxv = x_next - x_reg; x_reg = x_next;
            s_dx[(i + 1) & 1][bd][cd] = dxv;
            if (i + 2 < kT) {
                if (cd == 0) x_next = ts[i + 2];
                else { x_next = *yptr; yptr += kD; }
            }
        }
        __syncthreads();

        // ===== PhB: z1 int24 quantize + fragment write (waves 8-15) =====
        if (wv >= 8) {
            float gm = fmaxf(fmaxf(fmaxf(s_red[8], s_red[9]), fmaxf(s_red[10], s_red[11])),
                             fmaxf(fmaxf(s_red[12], s_red[13]), fmaxf(s_red[14], s_red[15])));
            float inv = (gm > 0.f) ? QA / gm : 0.f;
            if (wv == 8 && ln == 0) s_scales[1] = gm / QA;
            const int M = wv - 8;
            char* zb = (char*)s_z1q;
            #pragma unroll
            for (int r = 0; r < 4; r++) {
                int k = 16 * M + 4 * (ln >> 4) + r;
                int q = q24c(z1v[r], inv);
                int a0p, a1p, a2p; split24(q, a0p, a1p, a2p);
                int kc = k >> 6, lp = ((k & 63) >> 4) * 16 + bq, jj = k & 15;
                int off = kc * 3072 + lp * 16 + jj;
                zb[off]        = (char)a2p;
                zb[off + 1024] = (char)a1p;
                zb[off + 2048] = (char)a0p;
            }
        }
        __syncthreads();

        // ===== PhC: layer2 MFMA (waves 0-7) =====
        float z2v[4] = {0.f, 0.f, 0.f, 0.f};
        if (wv < 8) {
            const uint4* p = w1q + wv * 256 + ln;
            uint4 wh0 = p[0], wl0 = p[64], wh1 = p[128], wl1 = p[192];
            uint4 x20 = s_z1q[0][0][ln], x10 = s_z1q[0][1][ln], x00 = s_z1q[0][2][ln];
            uint4 x21 = s_z1q[1][0][ln], x11 = s_z1q[1][1][ln], x01 = s_z1q[1][2][ln];
            i32x4 A = mmi8(wh0, x20, zz); A = mmi8(wh1, x21, A);
            i32x4 B = mmi8(wh0, x10, zz); B = mmi8(wl0, x20, B);
            B = mmi8(wh1, x11, B); B = mmi8(wl1, x21, B);
            i32x4 C = mmi8(wh0, x00, zz); C = mmi8(wl0, x10, C);
            C = mmi8(wh1, x01, C); C = mmi8(wl1, x11, C);
            const float sz1 = s_scales[1];
            const int r0 = 16 * wv + 4 * (ln >> 4);
            float amC = 0.f;
            #pragma unroll
            for (int r = 0; r < 4; r++) {
                int rw = r0 + r;
                float raw = 16777216.f * (float)A[r] + 65536.f * (float)B[r] + 256.f * (float)C[r];
                float pre = scf[SC1W + rw] * sz1 * raw + vb1[rw];
                z2v[r] = lipswish_f(pre);
                amC = fmaxf(amC, fabsf(z2v[r]));
            }
            #pragma unroll
            for (int s = 1; s < 64; s <<= 1) amC = fmaxf(amC, __shfl_xor(amC, s));
            if (ln == 0) s_red[wv] = amC;
        }
        __syncthreads();

        // ===== PhD: z2 int24 quantize + fragment write (waves 0-7) =====
        if (wv < 8) {
            float gm = fmaxf(fmaxf(fmaxf(s_red[0], s_red[1]), fmaxf(s_red[2], s_red[3])),
                             fmaxf(fmaxf(s_red[4], s_red[5]), fmaxf(s_red[6], s_red[7])));
            float inv = (gm > 0.f) ? QA / gm : 0.f;
            if (wv == 0 && ln == 0) s_scales[2] = gm / QA;
            char* zb = (char*)s_z2q;
            #pragma unroll
            for (int r = 0; r < 4; r++) {
                int k = 16 * wv + 4 * (ln >> 4) + r;
                int q = q24c(z2v[r], inv);
                int a0p, a1p, a2p; split24(q, a0p, a1p, a2p);
                int kc = k >> 6, lp = ((k & 63) >> 4) * 16 + bq, jj = k & 15;
                int off = kc * 3072 + lp * 16 + jj;
                zb[off]        = (char)a2p;
                zb[off + 1024] = (char)a1p;
                zb[off + 2048] = (char)a0p;
            }
        }
        __syncthreads();

        // ===== PhE: layer3 (2112 rows) — all 16 waves, W2 streamed from L2 =====
        {
            const uint4 y20 = s_z2q[0][0][ln], y10 = s_z2q[0][1][ln], y00 = s_z2q[0][2][ln];
            const uint4 y21 = s_z2q[1][0][ln], y11 = s_z2q[1][1][ln], y01 = s_z2q[1][2][ln];
            const float sz2 = s_scales[2];
            const int nj = (wv < 4) ? 9 : 8;       // 132 = 16*8 + 4
            for (int j = 0; j < nj; j++) {
                const int Mt = wv + 16 * j;
                const uint4* p = w2q + (size_t)Mt * 256 + ln;
                uint4 wh0 = p[0], wl0 = p[64], wh1 = p[128], wl1 = p[192];
                i32x4 A = mmi8(wh0, y20, zz); A = mmi8(wh1, y21, A);
                i32x4 B = mmi8(wh0, y10, zz); B = mmi8(wl0, y20, B);
                B = mmi8(wh1, y11, B); B = mmi8(wl1, y21, B);
                i32x4 C = mmi8(wh0, y00, zz); C = mmi8(wl0, y10, C);
                C = mmi8(wh1, y01, C); C = mmi8(wl1, y11, C);
                const int r0 = 16 * Mt + 4 * (ln >> 4);
                #pragma unroll
                for (int r = 0; r < 4; r++) {
                    int rw = r0 + r;
                    float raw = 16777216.f * (float)A[r] + 65536.f * (float)B[r] + 256.f * (float)C[r];
                    float val = fast_tanh(fmaf(scf[SC2W + rw] * sz2, raw, vb2[rw]));
                    int q = (int)rintf(val * 32511.f);
                    int hq = (int)((unsigned)rw / 33u);
                    int cq = rw - hq * 33;
                    s_v[bq * 2178 + hq * 34 + cq] = (unsigned short)q;
                }
            }
        }
        __syncthreads();

        // ===== PhF: einsums + state update; thread (be,he) owns y[be][he] =====
        float yh_new = 0.f, amF = 0.f;
        {
            const int be = t & 15, he = t >> 4;
            const unsigned* vp32 = (const unsigned*)(s_v + be * 2178 + he * 34);
            const float* dx0 = &s_dx[i & 1][be][0];
            const float* dx1 = &s_dx[(i + 1) & 1][be][0];
            float E0 = 0.f, E1 = 0.f;
            #pragma unroll
            for (int qd = 0; qd < 16; qd++) {
                unsigned u = vp32[qd];
                float v0 = (float)(short)(u & 0xFFFFu);
                float v1 = (float)(short)(u >> 16);
                E0 += v0 * dx0[2 * qd] + v1 * dx0[2 * qd + 1];
                E1 += v0 * dx1[2 * qd] + v1 * dx1[2 * qd + 1];
            }
            {
                float v32 = (float)(short)((const unsigned short*)vp32)[32];
                E0 += v32 * dx0[32]; E1 += v32 * dx1[32];
            }
            E0 *= (1.f / 32511.f); E1 *= (1.f / 32511.f);
            const int id = be * 65 + he;
            if (i > 0) s_y[id] += 0.5f * (s_e[id] + E0);
            if (i < kT - 1) {
                s_e[id] = E1;
                yh_new = 2.f * s_y[id] - s_yh[id] + E1;
                s_yh[id] = yh_new;
                amF = fabsf(yh_new);
            }
        }
        #pragma unroll
        for (int s = 1; s < 64; s <<= 1) amF = fmaxf(amF, __shfl_xor(amF, s));
        if (ln == 0) s_red[wv] = amF;
        __syncthreads();

        // ===== PhG: yhat int24 quantize + fragment write for next step =====
        if (i < kT - 1) {
            const int be = t & 15, he = t >> 4;
            float gm = s_red[0];
            #pragma unroll
            for (int k = 1; k < 16; k++) gm = fmaxf(gm, s_red[k]);
            float inv = (gm > 0.f) ? QA / gm : 0.f;
            int q = q24c(yh_new, inv);
            int a0p, a1p, a2p; split24(q, a0p, a1p, a2p);
            int lp = (he >> 4) * 16 + be, jj = he & 15;
            char* ib = (char*)s_inpq;
            ib[lp * 16 + jj]        = (char)a2p;
            ib[1024 + lp * 16 + jj] = (char)a1p;
            ib[2048 + lp * 16 + jj] = (char)a0p;
            if (t == 0) s_scales[0] = gm / QA;
        }
        __syncthreads();
    }

    // ---- readout ----
    if (t < BPB) {
        float a = rb[0];
        #pragma unroll
        for (int h = 0; h < kH; h++) a += s_y[t * 65 + h] * rW[h];
        out[bG0 + t] = a;
    }
}

// ---- fallback (no workspace): straightforward f32 per-batch kernel ----
__global__ __launch_bounds__(BLOCK)
void cde_mono0(
    const float* __restrict__ ts,  const float* __restrict__ ys,
    const float* __restrict__ iW0, const float* __restrict__ ib0,
    const float* __restrict__ iW1, const float* __restrict__ ib1,
    const float* __restrict__ iW2, const float* __restrict__ ib2,
    const float* __restrict__ vW0, const float* __restrict__ vb0,
    const float* __restrict__ vW1, const float* __restrict__ vb1,
    const float* __restrict__ vW2, const float* __restrict__ vb2,
    const float* __restrict__ rW,  const float* __restrict__ rb,
    float* __restrict__ out)
{
    const int b  = blockIdx.x;
    const int t  = threadIdx.x;
    const int r8 = t >> 3;
    const int g  = t & 7;

    __shared__ __align__(16) float s_v[kO];
    __shared__ __align__(16) float s_z1[kW], s_z2[kW];
    __shared__ __align__(16) float s_inp[kIN + 1];
    __shared__ float s_y[kH], s_yhat[kH], s_e[kH];
    __shared__ float s_dx[kC];

    const float* ysb = ys + (size_t)b * kT * kD;
    const float bA  = vb2[t];
    const float bB  = vb2[t + 1024];
    const float bTl = (t < 512) ? vb2[2048 + r8] : 0.0f;

    float x_reg = 0.0f, x_next = 0.0f;
    if (t < kC) {
        x_reg  = (t == 0) ? ts[0] : ysb[t - 1];
        x_next = (t == 0) ? ts[1] : ysb[kD + (t - 1)];
        s_dx[t] = x_reg;
    }
    if (t == 0) s_inp[kIN] = 0.0f;
    __syncthreads();
    if (t < kW) {
        const float* wrow = iW0 + t * kC;
        float acc = ib0[t];
        #pragma unroll
        for (int c = 0; c < kC; c++) acc += wrow[c] * s_dx[c];
        s_z1[t] = fmaxf(acc, 0.0f);
    }
    __syncthreads();
    if (t < kW) {
        const float4* wr = (const float4*)(iW1 + t * kW);
        const float4* z4 = (const float4*)s_z1;
        float acc = ib1[t];
        #pragma unroll 8
        for (int q = 0; q < kW / 4; q++) acc += dot4(wr[q], z4[q]);
        s_z2[t] = fmaxf(acc, 0.0f);
    }
    __syncthreads();
    if (t < kH) {
        const float4* wr = (const float4*)(iW2 + t * kW);
        const float4* z4 = (const float4*)s_z2;
        float acc = ib2[t];
        #pragma unroll 8
        for (int q = 0; q < kW / 4; q++) acc += dot4(wr[q], z4[q]);
        s_y[t] = acc; s_yhat[t] = acc;
        s_inp[1 + t] = acc;
    }
    if (t == 0) s_inp[0] = x_reg;
    __syncthreads();

    for (int i = 0; i < kT; i++) {
        {
            float acc = 0.0f;
            const float* rowp = vW0 + r8 * kIN;
            #pragma unroll
            for (int m = 0; m < 5; m++) {
                int p = g + 8 * m;
                if (p < 33) {
                    float w0 = rowp[2 * p];
                    float w1 = (2 * p + 1 < kIN) ? rowp[2 * p + 1] : 0.0f;
                    acc += w0 * s_inp[2 * p] + w1 * s_inp[2 * p + 1];
                }
            }
            acc += __shfl_xor(acc, 1);
            acc += __shfl_xor(acc, 2);
            acc += __shfl_xor(acc, 4);
            if (g == 0) s_z1[r8] = lipswish_f(vb0[r8] + acc);
        }
        __syncthreads();
        {
            float acc = 0.0f;
            #pragma unroll
            for (int m = 0; m < 2; m++) {
                int ch = g + 8 * m;
                const float4* z4 = (const float4*)(s_z1 + 8 * ch);
                const float* wr = vW1 + r8 * kW + 8 * ch;
                acc += dot4(*(const float4*)wr, z4[0]) + dot4(*(const float4*)(wr + 4), z4[1]);
            }
            acc += __shfl_xor(acc, 1);
            acc += __shfl_xor(acc, 2);
            acc += __shfl_xor(acc, 4);
            if (g == 0) s_z2[r8] = lipswish_f(vb1[r8] + acc);
        }
        __syncthreads();
        {
            float acc0 = 0.0f, acc1 = 0.0f;
            #pragma unroll 2
            for (int m = 0; m < 8; m++) {
                const float4* z4 = (const float4*)(s_z2 + 16 * m);
                float4 z0 = z4[0], z1 = z4[1], z2 = z4[2], z3 = z4[3];
                const float4* rA = (const float4*)(vW2 + (size_t)t * kW + 16 * m);
                const float4* rB = (const float4*)(vW2 + (size_t)(t + 1024) * kW + 16 * m);
                acc0 += dot4(rA[0], z0) + dot4(rA[1], z1) + dot4(rA[2], z2) + dot4(rA[3], z3);
                acc1 += dot4(rB[0], z0) + dot4(rB[1], z1) + dot4(rB[2], z2) + dot4(rB[3], z3);
            }
            s_v[t]        = fast_tanh(bA + acc0);
            s_v[t + 1024] = fast_tanh(bB + acc1);
        }
        if (t < 512) {
            const float4* z4 = (const float4*)(s_z2 + 16 * g);
            const float4* wr = (const float4*)(vW2 + (size_t)(2048 + r8) * kW + 16 * g);
            float acc = dot4(wr[0], z4[0]) + dot4(wr[1], z4[1]) + dot4(wr[2], z4[2]) + dot4(wr[3], z4[3]);
            acc += __shfl_xor(acc, 1);
            acc += __shfl_xor(acc, 2);
            acc += __shfl_xor(acc, 4);
            if (g == 0) s_v[2048 + r8] = fast_tanh(bTl + acc);
        }
        __syncthreads();
        if (i > 0 && t < kH) {
            const float* vr = s_v + t * kC;
            float acc = 0.0f;
            #pragma unroll
            for (int c = 0; c < kC; c++) acc += vr[c] * s_dx[c];
            s_y[t] += 0.5f * (s_e[t] + acc);
        }
        __syncthreads();
        if (i < kT - 1) {
            if (t < kC) {
                float xi = x_next;
                s_dx[t] = xi - x_reg;
                x_reg = xi;
                if (i + 2 < kT)
                    x_next = (t == 0) ? ts[i + 2] : ysb[(size_t)(i + 2) * kD + (t - 1)];
            }
            __syncthreads();
            if (t < kH) {
                const float* vr = s_v + t * kC;
                float e = 0.0f;
                #pragma unroll
                for (int c = 0; c < kC; c++) e += vr[c] * s_dx[c];
                s_e[t] = e;
                float yh = 2.0f * s_y[t] - s_yhat[t] + e;
                s_yhat[t] = yh;
                s_inp[1 + t] = yh;
            }
            if (t == 0) s_inp[0] = x_reg;
            __syncthreads();
        }
    }
    __syncthreads();
    if (t == 0) {
        float acc = rb[0];
        #pragma unroll
        for (int h = 0; h < kH; h++) acc += s_y[h] * rW[h];
        out[b] = acc;
    }
}

extern "C" void kernel_launch(void* const* d_in, const int* in_sizes, int n_in,
                              void* d_out, int out_size, void* d_ws, size_t ws_size,
                              hipStream_t stream)
{
    const float* ts  = (const float*)d_in[0];
    const float* ys  = (const float*)d_in[1];
    const float* iW0 = (const float*)d_in[2];
    const float* ib0 = (const float*)d_in[3];
    const float* iW1 = (const float*)d_in[4];
    const float* ib1 = (const float*)d_in[5];
    const float* iW2 = (const float*)d_in[6];
    const float* ib2 = (const float*)d_in[7];
    const float* vW0 = (const float*)d_in[8];
    const float* vb0 = (const float*)d_in[9];
    const float* vW1 = (const float*)d_in[10];
    const float* vb1 = (const float*)d_in[11];
    const float* vW2 = (const float*)d_in[12];
    const float* vb2 = (const float*)d_in[13];
    const float* rW  = (const float*)d_in[14];
    const float* rb  = (const float*)d_in[15];

    if (ws_size >= (size_t)WS_TOT * 4) {
        hipLaunchKernelGGL(prep_kernel, dim3(kO + kW + kW), dim3(64), 0, stream,
                           vW0, vW1, vW2, (unsigned*)d_ws);
        hipLaunchKernelGGL(cde_kernel, dim3(NBLK), dim3(BLOCK), 0, stream,
                           ts, ys, iW0, ib0, iW1, ib1, iW2, ib2,
                           vW0, vb0, vW1, vb1, vW2, vb2, rW, rb,
                           (const unsigned*)d_ws, (float*)d_out);
    } else {
        hipLaunchKernelGGL(cde_mono0, dim3(kB), dim3(BLOCK), 0, stream,
                           ts, ys, iW0, ib0, iW1, ib1, iW2, ib2,
                           vW0, vb0, vW1, vb1, vW2, vb2, rW, rb, (float*)d_out);
    }
}